// Round 7
// baseline (292.829 us; speedup 1.0000x reference)
//
#include <hip/hip_runtime.h>

#define CDIM 64

typedef __attribute__((ext_vector_type(8))) short bf16x8;
typedef __attribute__((ext_vector_type(4))) float f32x4;

// round-to-nearest-even fp32 -> bf16 (as short)
__device__ __forceinline__ short bf16r(float f) {
    unsigned a = __float_as_uint(f);
    a = (a + 0x7fffu + ((a >> 16) & 1u)) >> 16;
    return (short)a;
}
// pack two fp32 as bf16 pair: first -> bits[15:0], second -> bits[31:16]
__device__ __forceinline__ unsigned bfpack(float lo, float hi) {
    unsigned a = __float_as_uint(lo);
    a = (a + 0x7fffu + ((a >> 16) & 1u)) >> 16;
    unsigned b = __float_as_uint(hi);
    b = (b + 0x7fffu + ((b >> 16) & 1u)) & 0xffff0000u;
    return a | b;
}

// --- pack x (fp32) -> bf16 pairs (u32 per 2 channels) ---
__global__ __launch_bounds__(256) void k_pack(const float* __restrict__ x,
                                              unsigned* __restrict__ xb32, size_t n2) {
    size_t t = (size_t)blockIdx.x * 256 + threadIdx.x;
    size_t stride = (size_t)gridDim.x * 256;
    for (size_t i = t; i < n2; i += stride) {
        float2 v = ((const float2*)x)[i];
        xb32[i] = bfpack(v.x, v.y);
    }
}

// ===== CSR build: zero per-edge global atomics (R3) =====
#define NPB_SHIFT 9                     // 512 nodes per bucket
#define BKN (1 << NPB_SHIFT)
#define BPAD 10240                      // record slots per bucket (mean 8163, sd 90)
#define PART_CH 2048                    // edges per k_part block

// block 0: init padded bucket cursors; blocks 1,2: pre-transpose weights to
// bf16 n-major (wtg[l][m][n][k]) so k_fused reads B-fragments straight from
// global (48KB, L2-broadcast).
__global__ __launch_bounds__(256) void k_prep(int* __restrict__ bkt_cursor, int n_buckets,
                                              const float* __restrict__ w1,
                                              const float* __restrict__ root1,
                                              const float* __restrict__ w2,
                                              const float* __restrict__ root2,
                                              short* __restrict__ wtg) {
    int tid = threadIdx.x;
    if (blockIdx.x == 0) {
        if (tid < n_buckets) bkt_cursor[tid] = tid * BPAD;
        return;
    }
    int l = blockIdx.x - 1;
    const float* s0 = l ? w2 : w1;
    const float* srcs[3] = {s0, s0 + 4096, l ? root2 : root1};
    short* o = wtg + (size_t)l * 3 * 4096;
    for (int i = tid; i < 12288; i += 256) {
        int m = i >> 12, r = i & 4095, k = r >> 6, n = r & 63;  // w row-major [k][n]
        o[(m << 12) + (n << 6) + k] = bf16r(srcs[m][r]);
    }
}

// phase A: bin edges -> bucket-major padded records (d<<32 | s<<15 | u15).
// R6: LDS-staged run writes. Previously each record was stored individually
// via an LDS cursor handout -> the ~10-record runs were written by different
// threads at different TIMES (partial-line writeback, R1's pathology in
// miniature). Now: handout places records in a 16KB LDS buffer in bucket-
// major order + records its global target; one cooperative sweep then emits
// consecutive addresses from consecutive threads -> wave-coalesced bursts.
__global__ __launch_bounds__(256) void k_part(const int* __restrict__ src,
                                              const int* __restrict__ dst,
                                              const float* __restrict__ u,
                                              int* __restrict__ bkt_cursor,
                                              unsigned long long* __restrict__ rec,
                                              int n_edges, int n_buckets) {
    __shared__ int cnt_s[256];
    __shared__ int excl_s[256];
    __shared__ int cur_s[256];
    __shared__ int goff_s[256];
    __shared__ int tot_s;
    __shared__ unsigned long long rec_s[PART_CH];   // 16KB
    __shared__ int tgt_s[PART_CH];                  // 8KB
    int tid = threadIdx.x;
    cnt_s[tid] = 0;
    __syncthreads();
    int e0 = blockIdx.x * PART_CH + tid * 8;
    int d[8], s[8];
    float uu[8];
    if (e0 + 8 <= n_edges) {
        int4 d0 = *(const int4*)(dst + e0), d1 = *(const int4*)(dst + e0 + 4);
        int4 s0 = *(const int4*)(src + e0), s1 = *(const int4*)(src + e0 + 4);
        float4 u0 = *(const float4*)(u + e0), u1 = *(const float4*)(u + e0 + 4);
        d[0]=d0.x; d[1]=d0.y; d[2]=d0.z; d[3]=d0.w; d[4]=d1.x; d[5]=d1.y; d[6]=d1.z; d[7]=d1.w;
        s[0]=s0.x; s[1]=s0.y; s[2]=s0.z; s[3]=s0.w; s[4]=s1.x; s[5]=s1.y; s[6]=s1.z; s[7]=s1.w;
        uu[0]=u0.x; uu[1]=u0.y; uu[2]=u0.z; uu[3]=u0.w; uu[4]=u1.x; uu[5]=u1.y; uu[6]=u1.z; uu[7]=u1.w;
    } else {
#pragma unroll
        for (int i = 0; i < 8; ++i) {
            int e = e0 + i;
            bool ok = e < n_edges;
            d[i] = ok ? dst[e] : -1;
            s[i] = ok ? src[e] : 0;
            uu[i] = ok ? u[e] : 0.f;
        }
    }
#pragma unroll
    for (int i = 0; i < 8; ++i)
        if (d[i] >= 0) atomicAdd(&cnt_s[d[i] >> NPB_SHIFT], 1);
    __syncthreads();
    // inclusive scan of bucket counts
    int c = cnt_s[tid];
    excl_s[tid] = c;
    __syncthreads();
    for (int off = 1; off < 256; off <<= 1) {
        int t = (tid >= off) ? excl_s[tid - off] : 0;
        __syncthreads();
        excl_s[tid] += t;
        __syncthreads();
    }
    int excl = excl_s[tid] - c;
    if (tid == 255) tot_s = excl_s[255];
    __syncthreads();
    excl_s[tid] = excl;
    cur_s[tid] = excl;
    goff_s[tid] = (tid < n_buckets && c) ? atomicAdd(&bkt_cursor[tid], c) : 0;
    __syncthreads();
    // handout into staged LDS (bucket-major order) + remember global target
#pragma unroll
    for (int i = 0; i < 8; ++i) {
        if (d[i] >= 0) {
            int b = d[i] >> NPB_SHIFT;
            int p = atomicAdd(&cur_s[b], 1);
            unsigned uq = (unsigned)(uu[i] * 32767.0f + 0.5f);
            rec_s[p] = ((unsigned long long)(unsigned)d[i] << 32)
                     | (unsigned long long)(((unsigned)s[i] << 15) | uq);
            tgt_s[p] = goff_s[b] + (p - excl_s[b]);
        }
    }
    __syncthreads();
    int tot = tot_s;
    for (int i = tid; i < tot; i += 256)
        rec[tgt_s[i]] = rec_s[i];   // consecutive tids -> consecutive targets per run
}

// tiny scan over bucket sizes -> dense em32 bases
__global__ __launch_bounds__(256) void k_bscan(const int* __restrict__ bkt_cursor,
                                               int* __restrict__ ebase,
                                               int* __restrict__ row_start,
                                               int n_buckets, int n_nodes) {
    __shared__ int sm[256];
    int tid = threadIdx.x;
    int v = (tid < n_buckets) ? (bkt_cursor[tid] - tid * BPAD) : 0;
    sm[tid] = v;
    __syncthreads();
    for (int off = 1; off < 256; off <<= 1) {
        int t = (tid >= off) ? sm[tid - off] : 0;
        __syncthreads();
        sm[tid] += t;
        __syncthreads();
    }
    if (tid < n_buckets) ebase[tid] = sm[tid] - v;   // exclusive
    if (tid == 255) row_start[n_nodes] = sm[255];    // grand total (= n_edges)
}

// phase B (R6): 8 sub-blocks per bucket (grid 196 -> 1568; old 196x1024 grid
// was 0.77 blocks/CU -- structurally unable to fill the machine). Each block
// streams the bucket's dense record list (65KB, L2/LLC-hot across the 8
// readers), filters to its 64-node sub-range, and hist/scan/scatters into its
// private 4KB em32 window. Sub-base = ebase[b] + #records below sub_lo,
// counted during the same stream. Still zero global atomics.
#define SUBS 8
__global__ __launch_bounds__(256) void k_scat2(const unsigned long long* __restrict__ rec,
                                               const int* __restrict__ bkt_cursor,
                                               const int* __restrict__ ebase,
                                               int* __restrict__ row_start,
                                               unsigned* __restrict__ em32,
                                               int n_nodes) {
    __shared__ int cnt_s[64];
    __shared__ int sc_s[64];
    __shared__ int below_s;
    int tid = threadIdx.x;
    int b = blockIdx.x >> 3;
    int sub = blockIdx.x & 7;
    int lo = (b << NPB_SHIFT) + (sub << 6);
    int nrec = bkt_cursor[b] - b * BPAD;
    const unsigned long long* r0 = rec + (size_t)b * BPAD;
    if (tid < 64) cnt_s[tid] = 0;
    if (tid == 0) below_s = 0;
    __syncthreads();
    int below = 0;
    for (int i = tid; i < nrec; i += 256) {
        int d = (int)(r0[i] >> 32);
        int rel = d - lo;
        if (d < lo) below++;
        else if (rel < 64) atomicAdd(&cnt_s[rel], 1);
    }
    if (below) atomicAdd(&below_s, below);
    __syncthreads();
    if (tid < 64) sc_s[tid] = cnt_s[tid];
    __syncthreads();
    for (int off = 1; off < 64; off <<= 1) {
        int t = (tid < 64 && tid >= off) ? sc_s[tid - off] : 0;
        __syncthreads();
        if (tid < 64) sc_s[tid] += t;
        __syncthreads();
    }
    int base = ebase[b] + below_s;
    if (tid < 64) {
        int excl = sc_s[tid] - cnt_s[tid];
        int node = lo + tid;
        if (node < n_nodes) row_start[node] = base + excl;
        cnt_s[tid] = excl;   // becomes cursor
    }
    __syncthreads();
    for (int i = tid; i < nrec; i += 256) {
        unsigned long long r = r0[i];
        int rel = (int)(r >> 32) - lo;
        if ((unsigned)rel < 64u) {
            int p = atomicAdd(&cnt_s[rel], 1);
            em32[base + p] = (unsigned)r;
        }
    }
}

// ===== R5/R6: fused layer kernel, quarter-wave aggregation =====
// R5: quarter-wave (16 lanes x uint2 = 64 ch) per node, 4 nodes in
// flight/wave, no shfl, no __syncthreads. R6: unroll 8 (32 outstanding
// gathers/wave, was 16) -- kernel measured latency-bound (VALUBusy 40%,
// occupancy grid-capped ~6 blocks/CU, 2.05 TB/s).
__global__ __launch_bounds__(256) void k_fused(
        const unsigned* __restrict__ xb_in,   // bf16 rows [n][32] u32 pairs
        const unsigned* __restrict__ em32,
        const int* __restrict__ row_start,
        const short* __restrict__ wb,         // [3][64][64] bf16 (n-major, k-contig)
        const float* __restrict__ bias,
        float* __restrict__ out,              // fp32 out (layer 2) or null
        unsigned short* __restrict__ xb_out,  // bf16 out (layer 1) or null
        int n_nodes) {
    __shared__ __align__(16) unsigned gl[64][68];  // [node][word]: 0..31=g0, 32..63=g1; pad->68
    int wave = threadIdx.x >> 6;
    int lane = threadIdx.x & 63;
    int q = lane >> 4;           // quarter = which node of the group of 4
    int ql = lane & 15;          // word-pair index: words 2ql,2ql+1 (channels 4ql..4ql+3)
    int nodew = blockIdx.x * 64 + wave * 16;
    const float inv15 = 1.0f / 32767.0f;

    // --- aggregation: quarter q handles nodes nodew + q*4 + t, t=0..3 ---
    for (int t = 0; t < 4; ++t) {
        int n = nodew + q * 4 + t;
        bool nok = n < n_nodes;
        int start = nok ? row_start[n] : 0;
        int end = nok ? row_start[n + 1] : 0;
        float a0 = 0.f, a1 = 0.f, a2 = 0.f, a3 = 0.f;   // g0, channels 4ql..4ql+3
        float b0 = 0.f, b1 = 0.f, b2 = 0.f, b3 = 0.f;   // g1
        int j = start;
        for (; j + 8 <= end; j += 8) {
            unsigned e[8];
            uint2 v[8];
#pragma unroll
            for (int i = 0; i < 8; ++i) e[i] = em32[j + i];
#pragma unroll
            for (int i = 0; i < 8; ++i)
                v[i] = *(const uint2*)(xb_in + (size_t)(e[i] >> 15) * 32 + 2 * ql);
#pragma unroll
            for (int i = 0; i < 8; ++i) {
                float uu = (float)(e[i] & 0x7fffu) * inv15;
                float wa = 1.0f - uu;
                float c0 = __uint_as_float(v[i].x << 16);
                float c1 = __uint_as_float(v[i].x & 0xffff0000u);
                float c2 = __uint_as_float(v[i].y << 16);
                float c3 = __uint_as_float(v[i].y & 0xffff0000u);
                a0 += wa * c0; a1 += wa * c1; a2 += wa * c2; a3 += wa * c3;
                b0 += uu * c0; b1 += uu * c1; b2 += uu * c2; b3 += uu * c3;
            }
        }
        if (j < end) {   // masked tail (1..7 edges)
            unsigned e[8];
            uint2 v[8];
            float m[8];
#pragma unroll
            for (int i = 0; i < 8; ++i) {
                int idx = j + i;
                bool ok = idx < end;
                e[i] = em32[ok ? idx : (end - 1)];
                m[i] = ok ? 1.0f : 0.0f;
            }
#pragma unroll
            for (int i = 0; i < 8; ++i)
                v[i] = *(const uint2*)(xb_in + (size_t)(e[i] >> 15) * 32 + 2 * ql);
#pragma unroll
            for (int i = 0; i < 8; ++i) {
                float uu = (float)(e[i] & 0x7fffu) * inv15;
                float wa = (1.0f - uu) * m[i], wu = uu * m[i];
                float c0 = __uint_as_float(v[i].x << 16);
                float c1 = __uint_as_float(v[i].x & 0xffff0000u);
                float c2 = __uint_as_float(v[i].y << 16);
                float c3 = __uint_as_float(v[i].y & 0xffff0000u);
                a0 += wa * c0; a1 += wa * c1; a2 += wa * c2; a3 += wa * c3;
                b0 += wu * c0; b1 += wu * c1; b2 += wu * c2; b3 += wu * c3;
            }
        }
        float s = 1.0f / fmaxf((float)(end - start), 1.0f);
        int row = wave * 16 + q * 4 + t;
        *(uint2*)&gl[row][2 * ql] = make_uint2(bfpack(a0 * s, a1 * s), bfpack(a2 * s, a3 * s));
        *(uint2*)&gl[row][32 + 2 * ql] = make_uint2(bfpack(b0 * s, b1 * s), bfpack(b2 * s, b3 * s));
    }
    // no __syncthreads: each wave's epilogue reads only rows its own lanes wrote

    // --- MFMA epilogue (m92-verified layout) ---
    int quad = lane >> 4;
    int m16 = lane & 15;
    int arow = nodew + m16;
    const short* gp = (const short*)&gl[wave * 16 + m16][0];
    const unsigned* xp = xb_in + (size_t)arow * 32;
    bf16x8 zf = {0, 0, 0, 0, 0, 0, 0, 0};
    bf16x8 aG0[2], aG1[2], aX[2];
#pragma unroll
    for (int kf = 0; kf < 2; ++kf) {
        aG0[kf] = *(const bf16x8*)(gp + kf * 32 + quad * 8);
        aG1[kf] = *(const bf16x8*)(gp + 64 + kf * 32 + quad * 8);
        aX[kf] = (arow < n_nodes) ? *(const bf16x8*)(xp + kf * 16 + quad * 4) : zf;
    }
#pragma unroll
    for (int nt = 0; nt < 4; ++nt) {
        f32x4 acc = {0.f, 0.f, 0.f, 0.f};
#pragma unroll
        for (int kf = 0; kf < 2; ++kf) {
            int col = nt * 16 + m16;
            bf16x8 bw0 = *(const bf16x8*)(wb + (col << 6) + kf * 32 + quad * 8);
            bf16x8 bw1 = *(const bf16x8*)(wb + ((64 + col) << 6) + kf * 32 + quad * 8);
            bf16x8 bwR = *(const bf16x8*)(wb + ((128 + col) << 6) + kf * 32 + quad * 8);
            acc = __builtin_amdgcn_mfma_f32_16x16x32_bf16(aG0[kf], bw0, acc, 0, 0, 0);
            acc = __builtin_amdgcn_mfma_f32_16x16x32_bf16(aG1[kf], bw1, acc, 0, 0, 0);
            acc = __builtin_amdgcn_mfma_f32_16x16x32_bf16(aX[kf], bwR, acc, 0, 0, 0);
        }
        float bcol = bias[nt * 16 + m16];
#pragma unroll
        for (int r = 0; r < 4; ++r) {
            int node = nodew + quad * 4 + r;
            if (node < n_nodes) {
                size_t off = (size_t)node * CDIM + nt * 16 + m16;
                float o = acc[r] + bcol;
                if (out) out[off] = o;
                if (xb_out) xb_out[off] = (unsigned short)bf16r(o);
            }
        }
    }
}

extern "C" void kernel_launch(void* const* d_in, const int* in_sizes, int n_in,
                              void* d_out, int out_size, void* d_ws, size_t ws_size,
                              hipStream_t stream) {
    const float* x = (const float*)d_in[0];
    const int* edge_index = (const int*)d_in[1];
    const float* edge_attr = (const float*)d_in[2];
    const float* w1 = (const float*)d_in[3];
    const float* root1 = (const float*)d_in[4];
    const float* b1 = (const float*)d_in[5];
    const float* w2 = (const float*)d_in[6];
    const float* root2 = (const float*)d_in[7];
    const float* b2 = (const float*)d_in[8];

    int n_nodes = in_sizes[0] / CDIM;
    int n_edges = in_sizes[2];
    const int* src = edge_index;
    const int* dst = edge_index + n_edges;

    size_t F = (size_t)n_nodes * CDIM;
    unsigned* xbA = (unsigned*)d_ws;              // F/2 u32: bf16(x)
    unsigned* xbB = xbA + F / 2;                  // F/2 u32: bf16(layer-1 out)
    unsigned* em32 = xbB + F / 2;                 // E u32 (src<<15 | u15)
    int* row_start = (int*)(em32 + n_edges);      // n+1
    int n_buckets = (n_nodes + BKN - 1) >> NPB_SHIFT;   // 196
    int* ebase = row_start + n_nodes + 1;         // n_buckets
    int* bkt_cursor = ebase + n_buckets;          // n_buckets
    uintptr_t p = (uintptr_t)(bkt_cursor + n_buckets);
    p = (p + 15) & ~(uintptr_t)15;
    short* wtg = (short*)p;                       // [2][3][64][64] bf16
    p += (size_t)2 * 3 * 4096 * sizeof(short);
    p = (p + 15) & ~(uintptr_t)15;
    unsigned long long* rec = (unsigned long long*)p;  // n_buckets*BPAD u64
    float* out = (float*)d_out;

    int gB = (n_nodes + 63) / 64;                 // 64 nodes per fused block
    int gP = (n_edges + PART_CH - 1) / PART_CH;   // 782

    // ---- CSR build + packs/preps ----
    k_pack<<<2048, 256, 0, stream>>>(x, xbA, F / 2);
    k_prep<<<3, 256, 0, stream>>>(bkt_cursor, n_buckets, w1, root1, w2, root2, wtg);
    k_part<<<gP, 256, 0, stream>>>(src, dst, edge_attr, bkt_cursor, rec, n_edges, n_buckets);
    k_bscan<<<1, 256, 0, stream>>>(bkt_cursor, ebase, row_start, n_buckets, n_nodes);
    k_scat2<<<n_buckets * SUBS, 256, 0, stream>>>(rec, bkt_cursor, ebase, row_start, em32, n_nodes);

    // ---- layer 1 (bf16 out only) ----
    k_fused<<<gB, 256, 0, stream>>>(xbA, em32, row_start, wtg, b1,
                                    nullptr, (unsigned short*)xbB, n_nodes);
    // ---- layer 2 (fp32 out) ----
    k_fused<<<gB, 256, 0, stream>>>(xbB, em32, row_start, wtg + 3 * 4096, b2,
                                    out, nullptr, n_nodes);
}